// Round 8
// baseline (64.266 us; speedup 1.0000x reference)
//
#include <hip/hip_runtime.h>

// OptimalTransportDepthLoss: B=65536 rows of D=256.
// loss = mean_b [ mean_i (P-Q)^2 + EMD2(P/sumP, Q/sumQ) ]
//
// EMD2 via rank formula over the stable merge of the two CDFs (validated
// rounds 3/4/6/7, absmax 0):
//   cp-emission at merged pos k:  coef = 2k - 4i - 1, 0 if i==255
//   cq-emission at merged pos k:  coef = 4i - 2k - 1, 0 if j==255
// with u = 4i - 2k - 1:  coef = ea ? -(u+2) : u, u += ea ? +2 : -2; last-elem
// zeroing via sentinel (2.0f) in the read-ahead head.
//
// Round 8: (a) launch_bounds(256,8) — round 7's (256,4) cost 13pts of
// occupancy for no regalloc benefit (VGPR=36); (b) 4-ary co-rank search:
// chain depth 9 -> 5 dependent LDS reads (3 independent probe-pairs per
// step), the dominant serial chain per round-6/7 analysis. Two rows per
// wave step-interleaved. Wave-private LDS, lgkmcnt waits only, DPP scans,
// b128 staging, register prefetch. f64 cross-row accumulation.

#define NW    4      // waves per block
#define DSZ   256    // histogram length
#define LROW  260    // padded LDS row: 256 vals + sentinel at [256] (+pad)

template <int CTRL, int RMASK, bool BC>
__device__ __forceinline__ float dpp_add(float x) {
    int t = __builtin_amdgcn_update_dpp(0, __float_as_int(x), CTRL, RMASK, 0xf, BC);
    return x + __int_as_float(t);
}

// wave64 inclusive scan
__device__ __forceinline__ float wave_scan(float x) {
    x = dpp_add<0x111, 0xf, true >(x);   // row_shr:1
    x = dpp_add<0x112, 0xf, true >(x);   // row_shr:2
    x = dpp_add<0x114, 0xf, true >(x);   // row_shr:4
    x = dpp_add<0x118, 0xf, true >(x);   // row_shr:8
    x = dpp_add<0x142, 0xa, false>(x);   // row_bcast:15 -> rows 1,3
    x = dpp_add<0x143, 0xc, false>(x);   // row_bcast:31 -> rows 2,3
    return x;
}

__device__ __forceinline__ float lane63(float x) {
    return __int_as_float(__builtin_amdgcn_readlane(__float_as_int(x), 63));
}

// pred(m) = (k0-1-m < 0) || cq[k0-1-m] <= cp[m]  — monotone false->true in m
__device__ __forceinline__ bool corank_pred(const float* cp, const float* cq,
                                            int k0, int m) {
    int j  = k0 - 1 - m;
    int jr = j < 0 ? 0 : j;
    float qv = cq[jr];
    float pv = cp[m];
    return (j < 0) || (qv <= pv);
}

__global__ __launch_bounds__(256, 8) void otdl_main(
    const float* __restrict__ P, const float* __restrict__ Q,
    double* __restrict__ partial, int B, int bpw)
{
    __shared__ float  s_cp[NW][2][LROW];
    __shared__ float  s_cq[NW][2][LROW];
    __shared__ double s_bsum[NW];

    const int tid  = threadIdx.x;
    const int wv   = tid >> 6;
    const int lane = tid & 63;
    const int wgl  = blockIdx.x * NW + wv;   // global wave id

    float* cpA = s_cp[wv][0];
    float* cqA = s_cq[wv][0];
    float* cpB = s_cp[wv][1];
    float* cqB = s_cq[wv][1];

    // +inf sentinels (real values <= ~1.0); ordered before first use by the
    // WAR lgkmcnt(0) wait inside the loop.
    if (lane == 0) {
        cpA[DSZ] = 2.0f; cqA[DSZ] = 2.0f;
        cpB[DSZ] = 2.0f; cqB[DSZ] = 2.0f;
    }

    double acc = 0.0;
    const int  k0      = lane * 8;           // this lane's merge diagonal
    const int  npair   = bpw >> 1;
    const long rowbase = (long)wgl * bpw;

    // preload pair 0
    float4 pv0, qv0, pv1, qv1, np0, nq0, np1, nq1;
    {
        long c0 = (rowbase     < B) ? rowbase     : (B - 1);
        long c1 = (rowbase + 1 < B) ? rowbase + 1 : (B - 1);
        pv0 = reinterpret_cast<const float4*>(P + c0 * DSZ)[lane];
        qv0 = reinterpret_cast<const float4*>(Q + c0 * DSZ)[lane];
        pv1 = reinterpret_cast<const float4*>(P + c1 * DSZ)[lane];
        qv1 = reinterpret_cast<const float4*>(Q + c1 * DSZ)[lane];
    }

    for (int p = 0; p < npair; ++p) {
        long b = rowbase + 2 * p;

        // ---- front-end both rows: MSE, sums, DPP scans ----
        float dx0 = pv0.x - qv0.x, dy0 = pv0.y - qv0.y;
        float dz0 = pv0.z - qv0.z, dw0 = pv0.w - qv0.w;
        float msel0 = dx0*dx0 + dy0*dy0 + dz0*dz0 + dw0*dw0;
        float dx1 = pv1.x - qv1.x, dy1 = pv1.y - qv1.y;
        float dz1 = pv1.z - qv1.z, dw1 = pv1.w - qv1.w;
        float msel1 = dx1*dx1 + dy1*dy1 + dz1*dz1 + dw1*dw1;

        float pl0 = pv0.x + pv0.y + pv0.z + pv0.w;
        float ql0 = qv0.x + qv0.y + qv0.z + qv0.w;
        float pl1 = pv1.x + pv1.y + pv1.z + pv1.w;
        float ql1 = qv1.x + qv1.y + qv1.z + qv1.w;

        float ps0 = wave_scan(pl0);
        float qs0 = wave_scan(ql0);
        float ps1 = wave_scan(pl1);
        float qs1 = wave_scan(ql1);

        float rp0 = 1.0f / lane63(ps0);
        float rq0 = 1.0f / lane63(qs0);
        float rp1 = 1.0f / lane63(ps1);
        float rq1 = 1.0f / lane63(qs1);
        float pe0 = ps0 - pl0, qe0 = qs0 - ql0;
        float pe1 = ps1 - pl1, qe1 = qs1 - ql1;

        float4 wP0 = make_float4((pe0 + pv0.x) * rp0,
                                 (pe0 + pv0.x + pv0.y) * rp0,
                                 (pe0 + pv0.x + pv0.y + pv0.z) * rp0,
                                 ps0 * rp0);
        float4 wQ0 = make_float4((qe0 + qv0.x) * rq0,
                                 (qe0 + qv0.x + qv0.y) * rq0,
                                 (qe0 + qv0.x + qv0.y + qv0.z) * rq0,
                                 qs0 * rq0);
        float4 wP1 = make_float4((pe1 + pv1.x) * rp1,
                                 (pe1 + pv1.x + pv1.y) * rp1,
                                 (pe1 + pv1.x + pv1.y + pv1.z) * rp1,
                                 ps1 * rp1);
        float4 wQ1 = make_float4((qe1 + qv1.x) * rq1,
                                 (qe1 + qv1.x + qv1.y) * rq1,
                                 (qe1 + qv1.x + qv1.y + qv1.z) * rq1,
                                 qs1 * rq1);

        // WAR: previous pair's trailing merge reads must drain
        asm volatile("s_waitcnt lgkmcnt(0)" ::: "memory");

        *reinterpret_cast<float4*>(&cpA[lane * 4]) = wP0;
        *reinterpret_cast<float4*>(&cqA[lane * 4]) = wQ0;
        *reinterpret_cast<float4*>(&cpB[lane * 4]) = wP1;
        *reinterpret_cast<float4*>(&cqB[lane * 4]) = wQ1;

        // RAW: staging visible before search/merge reads
        asm volatile("s_waitcnt lgkmcnt(0)" ::: "memory");

        // ---- prefetch next pair (hides under co-rank + merge) ----
        if (p + 1 < npair) {
            long c0 = (b + 2 < B) ? b + 2 : (B - 1);
            long c1 = (b + 3 < B) ? b + 3 : (B - 1);
            np0 = reinterpret_cast<const float4*>(P + c0 * DSZ)[lane];
            nq0 = reinterpret_cast<const float4*>(Q + c0 * DSZ)[lane];
            np1 = reinterpret_cast<const float4*>(P + c1 * DSZ)[lane];
            nq1 = reinterpret_cast<const float4*>(Q + c1 * DSZ)[lane];
        }

        // ---- 4-ary co-rank, both rows step-interleaved:
        //      smallest i in [lo,hi] with pred(i); pred(hi_init) true.
        //      4 quaternary steps: 257 -> 64 -> 16 -> 4 -> 1, +1 binary.
        int lo0 = k0 > DSZ ? k0 - DSZ : 0;
        int hi0 = k0 < DSZ ? k0 : DSZ;
        int lo1 = lo0, hi1 = hi0;
#pragma unroll
        for (int s = 0; s < 4; ++s) {
            int n0 = hi0 - lo0, n1 = hi1 - lo1;
            int q0 = n0 >> 2,   q1 = n1 >> 2;
            int a10 = lo0 + q0,        a11 = lo1 + q1;
            int a20 = lo0 + (n0 >> 1), a21 = lo1 + (n1 >> 1);
            int a30 = lo0 + n0 - q0,   a31 = lo1 + n1 - q1;
            bool p10 = corank_pred(cpA, cqA, k0, a10);
            bool p11 = corank_pred(cpB, cqB, k0, a11);
            bool p20 = corank_pred(cpA, cqA, k0, a20);
            bool p21 = corank_pred(cpB, cqB, k0, a21);
            bool p30 = corank_pred(cpA, cqA, k0, a30);
            bool p31 = corank_pred(cpB, cqB, k0, a31);
            hi0 = p10 ? a10 : (p20 ? a20 : (p30 ? a30 : hi0));
            lo0 = !p30 ? a30 + 1 : (!p20 ? a20 + 1 : (!p10 ? a10 + 1 : lo0));
            hi1 = p11 ? a11 : (p21 ? a21 : (p31 ? a31 : hi1));
            lo1 = !p31 ? a31 + 1 : (!p21 ? a21 + 1 : (!p11 ? a11 + 1 : lo1));
        }
        {   // final binary step (range <= 1)
            bool p0 = corank_pred(cpA, cqA, k0, lo0);
            bool p1 = corank_pred(cpB, cqB, k0, lo1);
            lo0 = p0 ? lo0 : lo0 + 1;
            lo1 = p1 ? lo1 : lo1 + 1;
        }

        // ---- 8 merge steps, both rows step-interleaved ----
        const float* pA0 = cpA + lo0;
        const float* pB0 = cqA + (k0 - lo0);
        const float* pA1 = cpB + lo1;
        const float* pB1 = cqB + (k0 - lo1);
        float u0 = (float)(4 * lo0 - 2 * k0 - 1);
        float u1 = (float)(4 * lo1 - 2 * k0 - 1);
        float a0 = pA0[0], c0 = pB0[0], an0 = pA0[1], cn0 = pB0[1];
        float a1 = pA1[0], c1 = pB1[0], an1 = pA1[1], cn1 = pB1[1];
        float e0 = 0.0f, e1 = 0.0f;
#pragma unroll
        for (int s = 0; s < 8; ++s) {
            bool  ea0  = a0 < c0;
            bool  ea1  = a1 < c1;
            float val0 = ea0 ? a0 : c0;
            float val1 = ea1 ? a1 : c1;
            float u20  = u0 + 2.0f;
            float u21  = u1 + 2.0f;
            float cf0  = ea0 ? -u20 : u0;
            float cf1  = ea1 ? -u21 : u1;
            bool  ls0  = ea0 ? (an0 == 2.0f) : (cn0 == 2.0f);
            bool  ls1  = ea1 ? (an1 == 2.0f) : (cn1 == 2.0f);
            cf0 = ls0 ? 0.0f : cf0;
            cf1 = ls1 ? 0.0f : cf1;
            e0 = fmaf(val0, cf0, e0);
            e1 = fmaf(val1, cf1, e1);
            u0 = ea0 ? u20 : (u0 - 2.0f);
            u1 = ea1 ? u21 : (u1 - 2.0f);
            pA0 += ea0 ? 1 : 0;  pB0 += ea0 ? 0 : 1;
            pA1 += ea1 ? 1 : 0;  pB1 += ea1 ? 0 : 1;
            a0 = ea0 ? an0 : a0;  c0 = ea0 ? c0 : cn0;
            a1 = ea1 ? an1 : a1;  c1 = ea1 ? c1 : cn1;
            an0 = pA0[1];  cn0 = pB0[1];
            an1 = pA1[1];  cn1 = pB1[1];
        }

        if (b     < B) acc += (double)(e0 + msel0 * (1.0f / 256.0f));
        if (b + 1 < B) acc += (double)(e1 + msel1 * (1.0f / 256.0f));
        pv0 = np0; qv0 = nq0;
        pv1 = np1; qv1 = nq1;
    }

    // ---- wave reduce (f64), then block reduce ----
#pragma unroll
    for (int off = 32; off; off >>= 1) {
        double o = __shfl_xor(acc, off, 64);
        acc += o;
    }
    if (lane == 0) s_bsum[wv] = acc;
    __syncthreads();
    if (tid == 0) {
        partial[blockIdx.x] = s_bsum[0] + s_bsum[1] + s_bsum[2] + s_bsum[3];
    }
}

__global__ __launch_bounds__(256) void otdl_reduce(
    const double* __restrict__ partial, int n, float* __restrict__ out, double invB)
{
    __shared__ double sdata[256];
    double a = 0.0;
    for (int i = threadIdx.x; i < n; i += 256) a += partial[i];
    sdata[threadIdx.x] = a;
    __syncthreads();
    for (int s2 = 128; s2 > 0; s2 >>= 1) {
        if (threadIdx.x < s2) sdata[threadIdx.x] += sdata[threadIdx.x + s2];
        __syncthreads();
    }
    if (threadIdx.x == 0) out[0] = (float)(sdata[0] * invB);
}

extern "C" void kernel_launch(void* const* d_in, const int* in_sizes, int n_in,
                              void* d_out, int out_size, void* d_ws, size_t ws_size,
                              hipStream_t stream)
{
    const float* P = (const float*)d_in[0];
    const float* Q = (const float*)d_in[1];
    float* out = (float*)d_out;
    double* partial = (double*)d_ws;

    int B = in_sizes[0] / DSZ;          // 65536
    const int blocks = 2048;
    const int totalWaves = blocks * NW; // 8192
    int bpw = (B + totalWaves - 1) / totalWaves;  // 8 (even)

    otdl_main<<<blocks, 256, 0, stream>>>(P, Q, partial, B, bpw);
    otdl_reduce<<<1, 256, 0, stream>>>(partial, blocks, out, 1.0 / (double)B);
}

// Round 9
// 45.718 us; speedup vs baseline: 1.4057x; 1.4057x over previous
//
#include <hip/hip_runtime.h>

// OptimalTransportDepthLoss: B=65536 rows of D=256.
// loss = mean_b [ mean_i (P-Q)^2 + EMD2(P/sumP, Q/sumQ) ]
//
// EMD2 via rank formula over the stable merge of the two CDFs (validated
// rounds 3/4/6/7, absmax 0):
//   cp-emission at merged pos k:  coef = 2k - 4i - 1  (0 if i==255)
//   cq-emission at merged pos k:  coef = 4i - 2k - 1  (0 if j==255)
// with u = 4i - 2k - 1:  coef = ea ? -(u+2) : u, u += ea ? +2 : -2.
// The i==255/j==255 zeroing fires ONLY at merged positions 510/511 (the two
// row maxima), i.e. lane 63's last two steps; the uncorrected contribution
// there is exactly +/-(cp255-cq255), so a single lane-63 correction
// e -= |cp255-cq255| replaces the per-step sentinel checks (round 9).
//
// Structure: 2 rows/wave step-interleaved (round 7), binary co-rank,
// wave-private LDS + lgkmcnt waits only, DPP scans, b128 staging, register
// prefetch, v_rcp normalization, f64 cross-row accumulation.
// Round-8 lesson: (256,8) + fat search spilled (WRITE_SIZE 59MB); this code's
// natural VGPR=36 fits the 64-cap, so (256,8) is safe here.

#define NW    4      // waves per block
#define DSZ   256    // histogram length
#define LROW  260    // padded LDS row: 256 vals + sentinel at [256] (+pad)

template <int CTRL, int RMASK, bool BC>
__device__ __forceinline__ float dpp_add(float x) {
    int t = __builtin_amdgcn_update_dpp(0, __float_as_int(x), CTRL, RMASK, 0xf, BC);
    return x + __int_as_float(t);
}

// wave64 inclusive scan
__device__ __forceinline__ float wave_scan(float x) {
    x = dpp_add<0x111, 0xf, true >(x);   // row_shr:1
    x = dpp_add<0x112, 0xf, true >(x);   // row_shr:2
    x = dpp_add<0x114, 0xf, true >(x);   // row_shr:4
    x = dpp_add<0x118, 0xf, true >(x);   // row_shr:8
    x = dpp_add<0x142, 0xa, false>(x);   // row_bcast:15 -> rows 1,3
    x = dpp_add<0x143, 0xc, false>(x);   // row_bcast:31 -> rows 2,3
    return x;
}

__device__ __forceinline__ float lane63(float x) {
    return __int_as_float(__builtin_amdgcn_readlane(__float_as_int(x), 63));
}

__global__ __launch_bounds__(256, 8) void otdl_main(
    const float* __restrict__ P, const float* __restrict__ Q,
    double* __restrict__ partial, int B, int bpw)
{
    __shared__ float  s_cp[NW][2][LROW];
    __shared__ float  s_cq[NW][2][LROW];
    __shared__ double s_bsum[NW];

    const int tid  = threadIdx.x;
    const int wv   = tid >> 6;
    const int lane = tid & 63;
    const int wgl  = blockIdx.x * NW + wv;   // global wave id

    float* cpA = s_cp[wv][0];
    float* cqA = s_cq[wv][0];
    float* cpB = s_cp[wv][1];
    float* cqB = s_cq[wv][1];

    // +inf sentinels (real values <= ~1.0); ordered before first use by the
    // WAR lgkmcnt(0) wait inside the loop.
    if (lane == 0) {
        cpA[DSZ] = 2.0f; cqA[DSZ] = 2.0f;
        cpB[DSZ] = 2.0f; cqB[DSZ] = 2.0f;
    }

    double acc = 0.0;
    const int  k0      = lane * 8;           // this lane's merge diagonal
    const int  npair   = bpw >> 1;
    const long rowbase = (long)wgl * bpw;
    const bool is63    = (lane == 63);

    // preload pair 0
    float4 pv0, qv0, pv1, qv1, np0, nq0, np1, nq1;
    {
        long c0 = (rowbase     < B) ? rowbase     : (B - 1);
        long c1 = (rowbase + 1 < B) ? rowbase + 1 : (B - 1);
        pv0 = reinterpret_cast<const float4*>(P + c0 * DSZ)[lane];
        qv0 = reinterpret_cast<const float4*>(Q + c0 * DSZ)[lane];
        pv1 = reinterpret_cast<const float4*>(P + c1 * DSZ)[lane];
        qv1 = reinterpret_cast<const float4*>(Q + c1 * DSZ)[lane];
    }

    for (int p = 0; p < npair; ++p) {
        long b = rowbase + 2 * p;

        // ---- front-end both rows: MSE, sums, DPP scans ----
        float dx0 = pv0.x - qv0.x, dy0 = pv0.y - qv0.y;
        float dz0 = pv0.z - qv0.z, dw0 = pv0.w - qv0.w;
        float msel0 = dx0*dx0 + dy0*dy0 + dz0*dz0 + dw0*dw0;
        float dx1 = pv1.x - qv1.x, dy1 = pv1.y - qv1.y;
        float dz1 = pv1.z - qv1.z, dw1 = pv1.w - qv1.w;
        float msel1 = dx1*dx1 + dy1*dy1 + dz1*dz1 + dw1*dw1;

        float pl0 = pv0.x + pv0.y + pv0.z + pv0.w;
        float ql0 = qv0.x + qv0.y + qv0.z + qv0.w;
        float pl1 = pv1.x + pv1.y + pv1.z + pv1.w;
        float ql1 = qv1.x + qv1.y + qv1.z + qv1.w;

        float ps0 = wave_scan(pl0);
        float qs0 = wave_scan(ql0);
        float ps1 = wave_scan(pl1);
        float qs1 = wave_scan(ql1);

        float rp0 = __builtin_amdgcn_rcpf(lane63(ps0));
        float rq0 = __builtin_amdgcn_rcpf(lane63(qs0));
        float rp1 = __builtin_amdgcn_rcpf(lane63(ps1));
        float rq1 = __builtin_amdgcn_rcpf(lane63(qs1));
        float pe0 = ps0 - pl0, qe0 = qs0 - ql0;
        float pe1 = ps1 - pl1, qe1 = qs1 - ql1;

        float4 wP0 = make_float4((pe0 + pv0.x) * rp0,
                                 (pe0 + pv0.x + pv0.y) * rp0,
                                 (pe0 + pv0.x + pv0.y + pv0.z) * rp0,
                                 ps0 * rp0);
        float4 wQ0 = make_float4((qe0 + qv0.x) * rq0,
                                 (qe0 + qv0.x + qv0.y) * rq0,
                                 (qe0 + qv0.x + qv0.y + qv0.z) * rq0,
                                 qs0 * rq0);
        float4 wP1 = make_float4((pe1 + pv1.x) * rp1,
                                 (pe1 + pv1.x + pv1.y) * rp1,
                                 (pe1 + pv1.x + pv1.y + pv1.z) * rp1,
                                 ps1 * rp1);
        float4 wQ1 = make_float4((qe1 + qv1.x) * rq1,
                                 (qe1 + qv1.x + qv1.y) * rq1,
                                 (qe1 + qv1.x + qv1.y + qv1.z) * rq1,
                                 qs1 * rq1);

        // WAR: previous pair's trailing merge reads must drain
        asm volatile("s_waitcnt lgkmcnt(0)" ::: "memory");

        *reinterpret_cast<float4*>(&cpA[lane * 4]) = wP0;
        *reinterpret_cast<float4*>(&cqA[lane * 4]) = wQ0;
        *reinterpret_cast<float4*>(&cpB[lane * 4]) = wP1;
        *reinterpret_cast<float4*>(&cqB[lane * 4]) = wQ1;

        // RAW: staging visible before search/merge reads
        asm volatile("s_waitcnt lgkmcnt(0)" ::: "memory");

        // ---- prefetch next pair (hides under co-rank + merge) ----
        if (p + 1 < npair) {
            long c0 = (b + 2 < B) ? b + 2 : (B - 1);
            long c1 = (b + 3 < B) ? b + 3 : (B - 1);
            np0 = reinterpret_cast<const float4*>(P + c0 * DSZ)[lane];
            nq0 = reinterpret_cast<const float4*>(Q + c0 * DSZ)[lane];
            np1 = reinterpret_cast<const float4*>(P + c1 * DSZ)[lane];
            nq1 = reinterpret_cast<const float4*>(Q + c1 * DSZ)[lane];
        }

        // ---- binary co-rank, both rows step-interleaved:
        //      smallest i in [lo,hi] with cq[k0-1-i] <= cp[i]
        int lo0 = k0 > DSZ ? k0 - DSZ : 0;
        int hi0 = k0 < DSZ ? k0 : DSZ;
        int lo1 = lo0, hi1 = hi0;
#pragma unroll
        for (int s = 0; s < 9; ++s) {
            int mid0 = (lo0 + hi0) >> 1;
            int mid1 = (lo1 + hi1) >> 1;
            int jm0 = k0 - 1 - mid0;
            int jm1 = k0 - 1 - mid1;
            int jr0 = jm0 < 0 ? 0 : jm0;
            int jr1 = jm1 < 0 ? 0 : jm1;
            float q0 = cqA[jr0];
            float c0 = cpA[mid0];
            float q1 = cqB[jr1];
            float c1 = cpB[mid1];
            bool pr0 = (jm0 < 0) || (q0 <= c0);
            bool pr1 = (jm1 < 0) || (q1 <= c1);
            hi0 = pr0 ? mid0 : hi0;  lo0 = pr0 ? lo0 : mid0 + 1;
            hi1 = pr1 ? mid1 : hi1;  lo1 = pr1 ? lo1 : mid1 + 1;
        }

        // ---- 8 merge steps, both rows step-interleaved (no sentinel
        //      checks; lane-63 end correction instead) ----
        const float* pA0 = cpA + lo0;
        const float* pB0 = cqA + (k0 - lo0);
        const float* pA1 = cpB + lo1;
        const float* pB1 = cqB + (k0 - lo1);
        float u0 = (float)(4 * lo0 - 2 * k0 - 1);
        float u1 = (float)(4 * lo1 - 2 * k0 - 1);
        float a0 = pA0[0], c0 = pB0[0], an0 = pA0[1], cn0 = pB0[1];
        float a1 = pA1[0], c1 = pB1[0], an1 = pA1[1], cn1 = pB1[1];
        float e0 = 0.0f, e1 = 0.0f;
#pragma unroll
        for (int s = 0; s < 8; ++s) {
            bool  ea0  = a0 < c0;
            bool  ea1  = a1 < c1;
            float val0 = ea0 ? a0 : c0;
            float val1 = ea1 ? a1 : c1;
            float u20  = u0 + 2.0f;
            float u21  = u1 + 2.0f;
            float cf0  = ea0 ? -u20 : u0;
            float cf1  = ea1 ? -u21 : u1;
            e0 = fmaf(val0, cf0, e0);
            e1 = fmaf(val1, cf1, e1);
            u0 = ea0 ? u20 : (u0 - 2.0f);
            u1 = ea1 ? u21 : (u1 - 2.0f);
            pA0 += ea0 ? 1 : 0;  pB0 += ea0 ? 0 : 1;
            pA1 += ea1 ? 1 : 0;  pB1 += ea1 ? 0 : 1;
            a0 = ea0 ? an0 : a0;  c0 = ea0 ? c0 : cn0;
            a1 = ea1 ? an1 : a1;  c1 = ea1 ? c1 : cn1;
            an0 = pA0[1];  cn0 = pB0[1];
            an1 = pA1[1];  cn1 = pB1[1];
        }

        // lane-63 correction: merged positions 510/511 hold the two row
        // maxima (cp255, cq255); their true coefs are 0, uncorrected sum
        // is +/-(cp255-cq255) -> subtract |cp255-cq255|.
        e0 -= is63 ? fabsf(wP0.w - wQ0.w) : 0.0f;
        e1 -= is63 ? fabsf(wP1.w - wQ1.w) : 0.0f;

        if (b     < B) acc += (double)(e0 + msel0 * (1.0f / 256.0f));
        if (b + 1 < B) acc += (double)(e1 + msel1 * (1.0f / 256.0f));
        pv0 = np0; qv0 = nq0;
        pv1 = np1; qv1 = nq1;
    }

    // ---- wave reduce (f64), then block reduce ----
#pragma unroll
    for (int off = 32; off; off >>= 1) {
        double o = __shfl_xor(acc, off, 64);
        acc += o;
    }
    if (lane == 0) s_bsum[wv] = acc;
    __syncthreads();
    if (tid == 0) {
        partial[blockIdx.x] = s_bsum[0] + s_bsum[1] + s_bsum[2] + s_bsum[3];
    }
}

__global__ __launch_bounds__(256) void otdl_reduce(
    const double* __restrict__ partial, int n, float* __restrict__ out, double invB)
{
    __shared__ double sdata[256];
    double a = 0.0;
    for (int i = threadIdx.x; i < n; i += 256) a += partial[i];
    sdata[threadIdx.x] = a;
    __syncthreads();
    for (int s2 = 128; s2 > 0; s2 >>= 1) {
        if (threadIdx.x < s2) sdata[threadIdx.x] += sdata[threadIdx.x + s2];
        __syncthreads();
    }
    if (threadIdx.x == 0) out[0] = (float)(sdata[0] * invB);
}

extern "C" void kernel_launch(void* const* d_in, const int* in_sizes, int n_in,
                              void* d_out, int out_size, void* d_ws, size_t ws_size,
                              hipStream_t stream)
{
    const float* P = (const float*)d_in[0];
    const float* Q = (const float*)d_in[1];
    float* out = (float*)d_out;
    double* partial = (double*)d_ws;

    int B = in_sizes[0] / DSZ;          // 65536
    const int blocks = 2048;
    const int totalWaves = blocks * NW; // 8192
    int bpw = (B + totalWaves - 1) / totalWaves;  // 8 (even)

    otdl_main<<<blocks, 256, 0, stream>>>(P, Q, partial, B, bpw);
    otdl_reduce<<<1, 256, 0, stream>>>(partial, blocks, out, 1.0 / (double)B);
}

// Round 10
// 43.576 us; speedup vs baseline: 1.4748x; 1.0491x over previous
//
#include <hip/hip_runtime.h>

// OptimalTransportDepthLoss: B=65536 rows of D=256.
// loss = mean_b [ mean_i (P-Q)^2 + EMD2(P/sumP, Q/sumQ) ]
//
// EMD2 via rank formula over the stable merge of the two CDFs (validated
// rounds 3..9, absmax 0):
//   cp-emission at merged pos k:  coef = 2k - 4i - 1  (0 if i==255)
//   cq-emission at merged pos k:  coef = 4i - 2k - 1  (0 if j==255)
// u = 4i - 2k - 1:  coef = ea ? -(u+2) : u, u += ea ? +2 : -2. The 255-elem
// zeroing fires only at merged pos 510/511 (both row maxima, lane 63):
// single correction e -= |cp255 - cq255| (read from LDS, round 9 validated).
//
// Round 10: pair-level software pipeline, double-buffered wave-private LDS:
//   iter p: FE+stage(p+1) -> issue G(p+2) -> corank+merge(p).
// The FE's ~200cy of pure VALU fills merge(p)'s dependent ds_read bubbles
// (round 9: VALUBusy 46% = half the time is LDS latency). No lgkmcnt asm:
// per-wave DS ops are in-order and staging->read distance is a full iter.
// Spill fixes (round 8/9 lesson, WRITE_SIZE tripwire): lane-63 correction
// from LDS not live regs, one G-load reg set, launch_bounds(256,4).

#define NW    4      // waves per block
#define DSZ   256    // histogram length
#define LROW  260    // 256 vals + sentinel at [256] (+pad)

template <int CTRL, int RMASK, bool BC>
__device__ __forceinline__ float dpp_add(float x) {
    int t = __builtin_amdgcn_update_dpp(0, __float_as_int(x), CTRL, RMASK, 0xf, BC);
    return x + __int_as_float(t);
}

// wave64 inclusive scan
__device__ __forceinline__ float wave_scan(float x) {
    x = dpp_add<0x111, 0xf, true >(x);   // row_shr:1
    x = dpp_add<0x112, 0xf, true >(x);   // row_shr:2
    x = dpp_add<0x114, 0xf, true >(x);   // row_shr:4
    x = dpp_add<0x118, 0xf, true >(x);   // row_shr:8
    x = dpp_add<0x142, 0xa, false>(x);   // row_bcast:15 -> rows 1,3
    x = dpp_add<0x143, 0xc, false>(x);   // row_bcast:31 -> rows 2,3
    return x;
}

__device__ __forceinline__ float lane63(float x) {
    return __int_as_float(__builtin_amdgcn_readlane(__float_as_int(x), 63));
}

// front-end one row: MSE partial + normalized CDF staged to LDS
__device__ __forceinline__ float fe_stage(const float4 pv, const float4 qv,
                                          float* cp, float* cq, int lane) {
    float dx = pv.x - qv.x, dy = pv.y - qv.y;
    float dz = pv.z - qv.z, dw = pv.w - qv.w;
    float msel = dx*dx + dy*dy + dz*dz + dw*dw;

    float pl = pv.x + pv.y + pv.z + pv.w;
    float ql = qv.x + qv.y + qv.z + qv.w;
    float ps = wave_scan(pl);
    float qs = wave_scan(ql);
    float rp = __builtin_amdgcn_rcpf(lane63(ps));
    float rq = __builtin_amdgcn_rcpf(lane63(qs));
    float pe = ps - pl, qe = qs - ql;

    float4 wP = make_float4((pe + pv.x) * rp,
                            (pe + pv.x + pv.y) * rp,
                            (pe + pv.x + pv.y + pv.z) * rp,
                            ps * rp);
    float4 wQ = make_float4((qe + qv.x) * rq,
                            (qe + qv.x + qv.y) * rq,
                            (qe + qv.x + qv.y + qv.z) * rq,
                            qs * rq);
    *reinterpret_cast<float4*>(&cp[lane * 4]) = wP;
    *reinterpret_cast<float4*>(&cq[lane * 4]) = wQ;
    return msel;
}

__global__ __launch_bounds__(256, 4) void otdl_main(
    const float* __restrict__ P, const float* __restrict__ Q,
    double* __restrict__ partial, int B, int bpw)
{
    __shared__ float  s_cp[NW][2][2][LROW];   // [wave][buf][row][...]
    __shared__ float  s_cq[NW][2][2][LROW];
    __shared__ double s_bsum[NW];

    const int tid  = threadIdx.x;
    const int wv   = tid >> 6;
    const int lane = tid & 63;
    const int wgl  = blockIdx.x * NW + wv;   // global wave id

    // +inf sentinels (real values <= ~1.0); wave-private, ordered by the
    // in-order DS pipe before any later read.
    if (lane == 0) {
#pragma unroll
        for (int bf = 0; bf < 2; ++bf)
#pragma unroll
            for (int r = 0; r < 2; ++r) {
                s_cp[wv][bf][r][DSZ] = 2.0f;
                s_cq[wv][bf][r][DSZ] = 2.0f;
            }
    }

    double acc = 0.0;
    const int  k0      = lane * 8;           // this lane's merge diagonal
    const int  npair   = bpw >> 1;
    const long rowbase = (long)wgl * bpw;
    const bool is63    = (lane == 63);

    // load pair 0
    float4 pv0, qv0, pv1, qv1;
    {
        long c0 = (rowbase     < B) ? rowbase     : (B - 1);
        long c1 = (rowbase + 1 < B) ? rowbase + 1 : (B - 1);
        pv0 = reinterpret_cast<const float4*>(P + c0 * DSZ)[lane];
        qv0 = reinterpret_cast<const float4*>(Q + c0 * DSZ)[lane];
        pv1 = reinterpret_cast<const float4*>(P + c1 * DSZ)[lane];
        qv1 = reinterpret_cast<const float4*>(Q + c1 * DSZ)[lane];
    }

    // prologue: FE+stage pair 0 -> buf0, then start loading pair 1
    float mselC0 = fe_stage(pv0, qv0, s_cp[wv][0][0], s_cq[wv][0][0], lane);
    float mselC1 = fe_stage(pv1, qv1, s_cp[wv][0][1], s_cq[wv][0][1], lane);
    if (npair > 1) {
        long bb = rowbase + 2;
        long c0 = (bb     < B) ? bb     : (B - 1);
        long c1 = (bb + 1 < B) ? bb + 1 : (B - 1);
        pv0 = reinterpret_cast<const float4*>(P + c0 * DSZ)[lane];
        qv0 = reinterpret_cast<const float4*>(Q + c0 * DSZ)[lane];
        pv1 = reinterpret_cast<const float4*>(P + c1 * DSZ)[lane];
        qv1 = reinterpret_cast<const float4*>(Q + c1 * DSZ)[lane];
    }

#pragma unroll 2
    for (int p = 0; p < npair; ++p) {
        const int cur = p & 1;

        // ---- FE+stage pair p+1 into the other buffer (pure VALU + DS
        //      writes; scheduler interleaves this under merge(p)'s reads) ----
        float mselN0 = 0.0f, mselN1 = 0.0f;
        if (p + 1 < npair) {
            mselN0 = fe_stage(pv0, qv0, s_cp[wv][cur ^ 1][0], s_cq[wv][cur ^ 1][0], lane);
            mselN1 = fe_stage(pv1, qv1, s_cp[wv][cur ^ 1][1], s_cq[wv][cur ^ 1][1], lane);
        }
        // ---- issue global loads for pair p+2 (consumed next iteration) ----
        if (p + 2 < npair) {
            long bb = rowbase + 2 * (p + 2);
            long c0 = (bb     < B) ? bb     : (B - 1);
            long c1 = (bb + 1 < B) ? bb + 1 : (B - 1);
            pv0 = reinterpret_cast<const float4*>(P + c0 * DSZ)[lane];
            qv0 = reinterpret_cast<const float4*>(Q + c0 * DSZ)[lane];
            pv1 = reinterpret_cast<const float4*>(P + c1 * DSZ)[lane];
            qv1 = reinterpret_cast<const float4*>(Q + c1 * DSZ)[lane];
        }

        const float* cpA = s_cp[wv][cur][0];
        const float* cqA = s_cq[wv][cur][0];
        const float* cpB = s_cp[wv][cur][1];
        const float* cqB = s_cq[wv][cur][1];

        // ---- binary co-rank, both rows step-interleaved:
        //      smallest i in [lo,hi] with cq[k0-1-i] <= cp[i]
        int lo0 = k0 > DSZ ? k0 - DSZ : 0;
        int hi0 = k0 < DSZ ? k0 : DSZ;
        int lo1 = lo0, hi1 = hi0;
#pragma unroll
        for (int s = 0; s < 9; ++s) {
            int mid0 = (lo0 + hi0) >> 1;
            int mid1 = (lo1 + hi1) >> 1;
            int jm0 = k0 - 1 - mid0;
            int jm1 = k0 - 1 - mid1;
            int jr0 = jm0 < 0 ? 0 : jm0;
            int jr1 = jm1 < 0 ? 0 : jm1;
            float q0 = cqA[jr0];
            float c0 = cpA[mid0];
            float q1 = cqB[jr1];
            float c1 = cpB[mid1];
            bool pr0 = (jm0 < 0) || (q0 <= c0);
            bool pr1 = (jm1 < 0) || (q1 <= c1);
            hi0 = pr0 ? mid0 : hi0;  lo0 = pr0 ? lo0 : mid0 + 1;
            hi1 = pr1 ? mid1 : hi1;  lo1 = pr1 ? lo1 : mid1 + 1;
        }

        // ---- 8 merge steps, both rows step-interleaved, sentinel-free ----
        const float* pA0 = cpA + lo0;
        const float* pB0 = cqA + (k0 - lo0);
        const float* pA1 = cpB + lo1;
        const float* pB1 = cqB + (k0 - lo1);
        float u0 = (float)(4 * lo0 - 2 * k0 - 1);
        float u1 = (float)(4 * lo1 - 2 * k0 - 1);
        float a0 = pA0[0], c0 = pB0[0], an0 = pA0[1], cn0 = pB0[1];
        float a1 = pA1[0], c1 = pB1[0], an1 = pA1[1], cn1 = pB1[1];
        float e0 = 0.0f, e1 = 0.0f;
#pragma unroll
        for (int s = 0; s < 8; ++s) {
            bool  ea0  = a0 < c0;
            bool  ea1  = a1 < c1;
            float val0 = ea0 ? a0 : c0;
            float val1 = ea1 ? a1 : c1;
            float u20  = u0 + 2.0f;
            float u21  = u1 + 2.0f;
            float cf0  = ea0 ? -u20 : u0;
            float cf1  = ea1 ? -u21 : u1;
            e0 = fmaf(val0, cf0, e0);
            e1 = fmaf(val1, cf1, e1);
            u0 = ea0 ? u20 : (u0 - 2.0f);
            u1 = ea1 ? u21 : (u1 - 2.0f);
            pA0 += ea0 ? 1 : 0;  pB0 += ea0 ? 0 : 1;
            pA1 += ea1 ? 1 : 0;  pB1 += ea1 ? 0 : 1;
            a0 = ea0 ? an0 : a0;  c0 = ea0 ? c0 : cn0;
            a1 = ea1 ? an1 : a1;  c1 = ea1 ? c1 : cn1;
            an0 = pA0[1];  cn0 = pB0[1];
            an1 = pA1[1];  cn1 = pB1[1];
        }

        // lane-63 correction: merged pos 510/511 hold the row maxima with
        // true coef 0; uncorrected sum is +/-(cp255-cq255). LDS broadcast
        // reads (uniform address), masked to lane 63 — no register liveness.
        e0 -= is63 ? fabsf(cpA[DSZ - 1] - cqA[DSZ - 1]) : 0.0f;
        e1 -= is63 ? fabsf(cpB[DSZ - 1] - cqB[DSZ - 1]) : 0.0f;

        long b = rowbase + 2 * p;
        if (b     < B) acc += (double)(e0 + mselC0 * (1.0f / 256.0f));
        if (b + 1 < B) acc += (double)(e1 + mselC1 * (1.0f / 256.0f));
        mselC0 = mselN0;
        mselC1 = mselN1;
    }

    // ---- wave reduce (f64), then block reduce ----
#pragma unroll
    for (int off = 32; off; off >>= 1) {
        double o = __shfl_xor(acc, off, 64);
        acc += o;
    }
    if (lane == 0) s_bsum[wv] = acc;
    __syncthreads();
    if (tid == 0) {
        partial[blockIdx.x] = s_bsum[0] + s_bsum[1] + s_bsum[2] + s_bsum[3];
    }
}

__global__ __launch_bounds__(256) void otdl_reduce(
    const double* __restrict__ partial, int n, float* __restrict__ out, double invB)
{
    __shared__ double sdata[256];
    double a = 0.0;
    for (int i = threadIdx.x; i < n; i += 256) a += partial[i];
    sdata[threadIdx.x] = a;
    __syncthreads();
    for (int s2 = 128; s2 > 0; s2 >>= 1) {
        if (threadIdx.x < s2) sdata[threadIdx.x] += sdata[threadIdx.x + s2];
        __syncthreads();
    }
    if (threadIdx.x == 0) out[0] = (float)(sdata[0] * invB);
}

extern "C" void kernel_launch(void* const* d_in, const int* in_sizes, int n_in,
                              void* d_out, int out_size, void* d_ws, size_t ws_size,
                              hipStream_t stream)
{
    const float* P = (const float*)d_in[0];
    const float* Q = (const float*)d_in[1];
    float* out = (float*)d_out;
    double* partial = (double*)d_ws;

    int B = in_sizes[0] / DSZ;          // 65536
    const int blocks = 2048;
    const int totalWaves = blocks * NW; // 8192
    int bpw = (B + totalWaves - 1) / totalWaves;  // 8 (even)

    otdl_main<<<blocks, 256, 0, stream>>>(P, Q, partial, B, bpw);
    otdl_reduce<<<1, 256, 0, stream>>>(partial, blocks, out, 1.0 / (double)B);
}

// Round 11
// 41.412 us; speedup vs baseline: 1.5518x; 1.0523x over previous
//
#include <hip/hip_runtime.h>

// OptimalTransportDepthLoss: B=65536 rows of D=256.
// loss = mean_b [ mean_i (P-Q)^2 + EMD2(P/sumP, Q/sumQ) ]
//
// EMD2 via rank formula over the stable merge of the two CDFs (validated
// rounds 3..10, absmax 0):
//   cp-emission at merged pos k:  coef = 2k - 4i - 1  (0 if i==255)
//   cq-emission at merged pos k:  coef = 4i - 2k - 1  (0 if j==255)
// u = 4i - 2k - 1:  coef = ea ? -(u+2) : u, u += ea ? +2 : -2. The 255-elem
// zeroing fires only at merged pos 510/511 (both row maxima, lane 63):
// single correction e -= |cp255 - cq255| read from LDS (round 9/10).
//
// Round 11: keep round-10's software pipeline (FE+stage(r+1) || merge(r),
// no lgkmcnt asm — per-wave DS ops are in-order, staging->read distance is
// a full iteration) but at ONE row per wave: LDS 33.8 -> 16.7 KB/block and
// launch_bounds(256,8) restore occupancy (round 10: pipeline won while
// starved at 32% occupancy / 4 blocks/CU). Chains/CU conserved (32x1 vs
// 16x2); TLP now fills the ds_read bubbles. Spill tripwire (WRITE_SIZE)
// was clean at VGPR=52; 1-row state is smaller still.

#define NW    4      // waves per block
#define DSZ   256    // histogram length
#define LROW  260    // 256 vals + sentinel at [256] (+pad)

template <int CTRL, int RMASK, bool BC>
__device__ __forceinline__ float dpp_add(float x) {
    int t = __builtin_amdgcn_update_dpp(0, __float_as_int(x), CTRL, RMASK, 0xf, BC);
    return x + __int_as_float(t);
}

// wave64 inclusive scan
__device__ __forceinline__ float wave_scan(float x) {
    x = dpp_add<0x111, 0xf, true >(x);   // row_shr:1
    x = dpp_add<0x112, 0xf, true >(x);   // row_shr:2
    x = dpp_add<0x114, 0xf, true >(x);   // row_shr:4
    x = dpp_add<0x118, 0xf, true >(x);   // row_shr:8
    x = dpp_add<0x142, 0xa, false>(x);   // row_bcast:15 -> rows 1,3
    x = dpp_add<0x143, 0xc, false>(x);   // row_bcast:31 -> rows 2,3
    return x;
}

__device__ __forceinline__ float lane63(float x) {
    return __int_as_float(__builtin_amdgcn_readlane(__float_as_int(x), 63));
}

// front-end one row: MSE partial + normalized CDF staged to LDS
__device__ __forceinline__ float fe_stage(const float4 pv, const float4 qv,
                                          float* cp, float* cq, int lane) {
    float dx = pv.x - qv.x, dy = pv.y - qv.y;
    float dz = pv.z - qv.z, dw = pv.w - qv.w;
    float msel = dx*dx + dy*dy + dz*dz + dw*dw;

    float pl = pv.x + pv.y + pv.z + pv.w;
    float ql = qv.x + qv.y + qv.z + qv.w;
    float ps = wave_scan(pl);
    float qs = wave_scan(ql);
    float rp = __builtin_amdgcn_rcpf(lane63(ps));
    float rq = __builtin_amdgcn_rcpf(lane63(qs));
    float pe = ps - pl, qe = qs - ql;

    float4 wP = make_float4((pe + pv.x) * rp,
                            (pe + pv.x + pv.y) * rp,
                            (pe + pv.x + pv.y + pv.z) * rp,
                            ps * rp);
    float4 wQ = make_float4((qe + qv.x) * rq,
                            (qe + qv.x + qv.y) * rq,
                            (qe + qv.x + qv.y + qv.z) * rq,
                            qs * rq);
    *reinterpret_cast<float4*>(&cp[lane * 4]) = wP;
    *reinterpret_cast<float4*>(&cq[lane * 4]) = wQ;
    return msel;
}

__global__ __launch_bounds__(256, 8) void otdl_main(
    const float* __restrict__ P, const float* __restrict__ Q,
    double* __restrict__ partial, int B, int bpw)
{
    __shared__ float  s_cp[NW][2][LROW];   // [wave][buf][...]
    __shared__ float  s_cq[NW][2][LROW];
    __shared__ double s_bsum[NW];

    const int tid  = threadIdx.x;
    const int wv   = tid >> 6;
    const int lane = tid & 63;
    const int wgl  = blockIdx.x * NW + wv;   // global wave id

    // +inf sentinels (real values <= ~1.0); wave-private, ordered by the
    // in-order DS pipe before any later read.
    if (lane == 0) {
        s_cp[wv][0][DSZ] = 2.0f; s_cq[wv][0][DSZ] = 2.0f;
        s_cp[wv][1][DSZ] = 2.0f; s_cq[wv][1][DSZ] = 2.0f;
    }

    double acc = 0.0;
    const int  k0      = lane * 8;           // this lane's merge diagonal
    const long rowbase = (long)wgl * bpw;
    const bool is63    = (lane == 63);

    // load row 0
    float4 pv, qv;
    {
        long c = (rowbase < B) ? rowbase : (B - 1);
        pv = reinterpret_cast<const float4*>(P + c * DSZ)[lane];
        qv = reinterpret_cast<const float4*>(Q + c * DSZ)[lane];
    }

    // prologue: FE+stage row 0 -> buf0, then load row 1
    float mselC = fe_stage(pv, qv, s_cp[wv][0], s_cq[wv][0], lane);
    if (bpw > 1) {
        long c = (rowbase + 1 < B) ? rowbase + 1 : (B - 1);
        pv = reinterpret_cast<const float4*>(P + c * DSZ)[lane];
        qv = reinterpret_cast<const float4*>(Q + c * DSZ)[lane];
    }

#pragma unroll 2
    for (int r = 0; r < bpw; ++r) {
        const int cur = r & 1;

        // ---- FE+stage row r+1 into the other buffer (pure VALU + DS
        //      writes; scheduler interleaves under merge(r)'s reads) ----
        float mselN = 0.0f;
        if (r + 1 < bpw) {
            mselN = fe_stage(pv, qv, s_cp[wv][cur ^ 1], s_cq[wv][cur ^ 1], lane);
        }
        // ---- issue global loads for row r+2 (consumed next iteration) ----
        if (r + 2 < bpw) {
            long c = (rowbase + r + 2 < B) ? rowbase + r + 2 : (B - 1);
            pv = reinterpret_cast<const float4*>(P + c * DSZ)[lane];
            qv = reinterpret_cast<const float4*>(Q + c * DSZ)[lane];
        }

        const float* cp = s_cp[wv][cur];
        const float* cq = s_cq[wv][cur];

        // ---- binary co-rank: smallest i in [lo,hi] with cq[k0-1-i] <= cp[i]
        int lo = k0 > DSZ ? k0 - DSZ : 0;
        int hi = k0 < DSZ ? k0 : DSZ;
#pragma unroll
        for (int s = 0; s < 9; ++s) {
            int mid = (lo + hi) >> 1;
            int jm  = k0 - 1 - mid;
            int jr  = jm < 0 ? 0 : jm;
            float qv_ = cq[jr];
            float cv_ = cp[mid];
            bool pred = (jm < 0) || (qv_ <= cv_);
            hi = pred ? mid : hi;
            lo = pred ? lo  : mid + 1;
        }

        // ---- 8 merge steps, sentinel-free (lane-63 end correction) ----
        const float* pA = cp + lo;
        const float* pB = cq + (k0 - lo);
        float u  = (float)(4 * lo - 2 * k0 - 1);
        float a  = pA[0];
        float b2 = pB[0];
        float an = pA[1];
        float bn = pB[1];
        float e_ = 0.0f;
#pragma unroll
        for (int s = 0; s < 8; ++s) {
            bool  ea   = a < b2;
            float val  = ea ? a : b2;
            float u2   = u + 2.0f;
            float coef = ea ? -u2 : u;
            e_ = fmaf(val, coef, e_);
            u  = ea ? u2 : (u - 2.0f);
            pA += ea ? 1 : 0;
            pB += ea ? 0 : 1;
            a  = ea ? an : a;
            b2 = ea ? b2 : bn;
            an = pA[1];
            bn = pB[1];
        }

        // lane-63 correction: merged pos 510/511 hold the row maxima with
        // true coef 0; uncorrected sum is +/-(cp255-cq255).
        e_ -= is63 ? fabsf(cp[DSZ - 1] - cq[DSZ - 1]) : 0.0f;

        if (rowbase + r < B) acc += (double)(e_ + mselC * (1.0f / 256.0f));
        mselC = mselN;
    }

    // ---- wave reduce (f64), then block reduce ----
#pragma unroll
    for (int off = 32; off; off >>= 1) {
        double o = __shfl_xor(acc, off, 64);
        acc += o;
    }
    if (lane == 0) s_bsum[wv] = acc;
    __syncthreads();
    if (tid == 0) {
        partial[blockIdx.x] = s_bsum[0] + s_bsum[1] + s_bsum[2] + s_bsum[3];
    }
}

__global__ __launch_bounds__(256) void otdl_reduce(
    const double* __restrict__ partial, int n, float* __restrict__ out, double invB)
{
    __shared__ double sdata[256];
    double a = 0.0;
    for (int i = threadIdx.x; i < n; i += 256) a += partial[i];
    sdata[threadIdx.x] = a;
    __syncthreads();
    for (int s2 = 128; s2 > 0; s2 >>= 1) {
        if (threadIdx.x < s2) sdata[threadIdx.x] += sdata[threadIdx.x + s2];
        __syncthreads();
    }
    if (threadIdx.x == 0) out[0] = (float)(sdata[0] * invB);
}

extern "C" void kernel_launch(void* const* d_in, const int* in_sizes, int n_in,
                              void* d_out, int out_size, void* d_ws, size_t ws_size,
                              hipStream_t stream)
{
    const float* P = (const float*)d_in[0];
    const float* Q = (const float*)d_in[1];
    float* out = (float*)d_out;
    double* partial = (double*)d_ws;

    int B = in_sizes[0] / DSZ;          // 65536
    const int blocks = 2048;
    const int totalWaves = blocks * NW; // 8192
    int bpw = (B + totalWaves - 1) / totalWaves;  // 8

    otdl_main<<<blocks, 256, 0, stream>>>(P, Q, partial, B, bpw);
    otdl_reduce<<<1, 256, 0, stream>>>(partial, blocks, out, 1.0 / (double)B);
}